// Round 1
// baseline (422.604 us; speedup 1.0000x reference)
//
#include <hip/hip_runtime.h>
#include <hip/hip_bf16.h>

#define U_NUM 100000
#define I_NUM 50000
#define N_NUM 150000
#define E_NUM 1200000
#define D 64
#define F_IT 384
#define CAP 32
#define EPSV 1e-8f
#define FXS 524288.0f          // 2^19 fixed-point scale (deterministic int accumulation)
#define FXI (1.0f / 524288.0f)

// ---- two-level binning geometry (replaces global-atomic bucket fill) ----
#define NBIN 586        // bins of 256 rows: 586*256 = 150016 >= N_NUM
#define RPB 256         // rows per bin (pow2: bin = row >> 8)
#define FBLK 586        // fill blocks, 2048 edges each (8 edges/thread)
#define CELL_CAP 16     // per (fill-block, bin) cell capacity; lambda=3.5, P(>16)~2e-7
#define OV_CAP 64       // per-bin overflow side-list capacity (expected use ~0)

typedef unsigned short ushort_t;
typedef unsigned int uint_t;
typedef short bf16x8 __attribute__((ext_vector_type(8)));
typedef float f32x4 __attribute__((ext_vector_type(4)));

__device__ __forceinline__ ushort_t f2bf(float f) {
    uint_t x = __float_as_uint(f);
    uint_t r = x + 0x7fffu + ((x >> 16) & 1u);   // round-to-nearest-even
    return (ushort_t)(r >> 16);
}
__device__ __forceinline__ float bfu2f(uint_t u_lo16) {
    return __uint_as_float(u_lo16 << 16);
}
__device__ __forceinline__ void dec8(uint4 u, float* f) {
    f[0] = bfu2f(u.x & 0xffffu); f[1] = bfu2f(u.x >> 16);
    f[2] = bfu2f(u.y & 0xffffu); f[3] = bfu2f(u.y >> 16);
    f[4] = bfu2f(u.z & 0xffffu); f[5] = bfu2f(u.z >> 16);
    f[6] = bfu2f(u.w & 0xffffu); f[7] = bfu2f(u.w >> 16);
}

// ================= prep: cast weights + sum global embs + zero ovcnt ===============
// (cnt zeroing no longer needed: k_bucket writes cnt for every row)
__global__ void k_prep(const float* __restrict__ w, const float* __restrict__ gu,
                       const float* __restrict__ gi,
                       short* __restrict__ wbf, float* __restrict__ gsu,
                       float* __restrict__ gsi, int* __restrict__ ovcnt) {
    int b = blockIdx.x, t = threadIdx.x;
    if (b < 96) {
        int i = b * 256 + t;   // exactly 96*256 = 24576 = D*F_IT
        wbf[i] = (short)f2bf(w[i]);
    } else {
        if (t < 64) gsu[t] = gu[t] + gu[64 + t] + gu[128 + t];
        else if (t < 128) { int d = t - 64; gsi[d] = gi[d] + gi[64 + d] + gi[128 + d]; }
        for (int i = t; i < NBIN; i += 256) ovcnt[i] = 0;
    }
}

// ================= mega: edge binning (LDS atomics) + item MLP + user, overlapped ==
// role striping per 9-block group: 2 fill, 2 item, 5 user.
// fill: NO global atomics — LDS slot allocation into private contiguous cells.
#define ITEM_B 782    // ceil(I/64)
#define USER_B 1563   // ceil(U*D/16/256)

__global__ __launch_bounds__(256) void k_mega(
        const int* __restrict__ row, const int* __restrict__ col,
        const float* __restrict__ val,
        const float* __restrict__ ufea, const float* __restrict__ ifea,
        const float* __restrict__ bvec,
        const short* __restrict__ wbf,
        const float* __restrict__ gsu, const float* __restrict__ gsi,
        int2* __restrict__ cellbuf, int* __restrict__ cellcnt,
        int* __restrict__ ovcnt, int2* __restrict__ ovbuf,
        float* __restrict__ ego, ushort_t* __restrict__ egob) {
    __shared__ int bincnt[NBIN];
    int b = blockIdx.x;
    int grp = b / 9, slot = b % 9;
    int tid = threadIdx.x;

    if (slot < 2) {
        // ---------------- fill role: bin 2048 edges via LDS counters ----------------
        int fid = grp * 2 + slot;
        if (fid >= FBLK) return;
        for (int i = tid; i < NBIN; i += 256) bincnt[i] = 0;
        __syncthreads();
        int t = fid * 256 + tid;              // < 150016
        if (t < E_NUM / 8) {                  // E/8 = 150000
#pragma unroll
            for (int k = 0; k < 8; k++) {
                int e = k * (E_NUM / 8) + t;  // strided, coalesced
                int r = row[e], c = col[e];
                float v = val[e];
                int bn = r >> 8;
                int key = c | ((r & 255) << 18);   // col:18b | row_local:8b
                int ls = atomicAdd(&bincnt[bn], 1);      // LDS atomic (fast)
                if (ls < CELL_CAP) {
                    cellbuf[((size_t)fid * NBIN + bn) * CELL_CAP + ls] =
                        make_int2(key, __float_as_int(v));
                } else {
                    int o = atomicAdd(&ovcnt[bn], 1);    // rare global fallback
                    if (o < OV_CAP) ovbuf[bn * OV_CAP + o] = make_int2(key, __float_as_int(v));
                }
            }
        }
        __syncthreads();
        // cellcnt layout [fid][bin] -> contiguous coalesced write per block
        for (int i = tid; i < NBIN; i += 256)
            cellcnt[(size_t)fid * NBIN + i] = min(bincnt[i], CELL_CAP);
    } else if (slot < 4) {
        // ---------------- item MLP role (MFMA, no LDS) ----------------
        int iid = grp * 2 + (slot - 2);
        if (iid >= ITEM_B) return;
        int wave = tid >> 6, lane = tid & 63;
        int q = lane >> 4, m = lane & 15;
        int ibase = iid * 64 + wave * 16;
        int irow = min(ibase + m, I_NUM - 1);
        const float* arow = ifea + (size_t)irow * F_IT + q * 8;

        f32x4 av[4];
#pragma unroll
        for (int n = 0; n < 4; n++) av[n] = (f32x4){0.f, 0.f, 0.f, 0.f};
#pragma unroll
        for (int c = 0; c < 12; c++) {
            float4 fa0 = ((const float4*)(arow + c * 32))[0];
            float4 fa1 = ((const float4*)(arow + c * 32))[1];
            bf16x8 af;
            af[0] = (short)f2bf(fa0.x); af[1] = (short)f2bf(fa0.y);
            af[2] = (short)f2bf(fa0.z); af[3] = (short)f2bf(fa0.w);
            af[4] = (short)f2bf(fa1.x); af[5] = (short)f2bf(fa1.y);
            af[6] = (short)f2bf(fa1.z); af[7] = (short)f2bf(fa1.w);
#pragma unroll
            for (int n = 0; n < 4; n++) {
                bf16x8 bf = *(const bf16x8*)(wbf + (size_t)(n * 16 + m) * F_IT + c * 32 + q * 8);
                av[n] = __builtin_amdgcn_mfma_f32_16x16x32_bf16(af, bf, av[n], 0, 0, 0);
            }
        }
        // C/D: col = lane&15 (dim), row = (lane>>4)*4 + reg (item)
#pragma unroll
        for (int n = 0; n < 4; n++) {
            int dim = n * 16 + m;
            float bb = bvec[dim];
            float gg = gsi[dim];
#pragma unroll
            for (int rr = 0; rr < 4; rr++) {
                int item = ibase + q * 4 + rr;
                if (item < I_NUM) {
                    float v = tanhf(av[n][rr] + bb) + gg;
                    size_t o = (size_t)(U_NUM + item) * D + dim;
                    ego[o] = v;
                    egob[o] = f2bf(v);
                }
            }
        }
    } else {
        // ---------------- user role: 16 floats/thread ----------------
        int uid = grp * 5 + (slot - 4);
        if (uid >= USER_B) return;
        int t = uid * 256 + tid;
        size_t base = (size_t)t * 16;
        if (base >= (size_t)U_NUM * D) return;
        int d0 = (int)(base & 63);
        float f[16];
#pragma unroll
        for (int k = 0; k < 4; k++) {
            float4 v = ((const float4*)(ufea + base))[k];
            f[4 * k] = v.x; f[4 * k + 1] = v.y; f[4 * k + 2] = v.z; f[4 * k + 3] = v.w;
        }
#pragma unroll
        for (int j = 0; j < 16; j++) f[j] += gsu[d0 + j];
#pragma unroll
        for (int k = 0; k < 4; k++) {
            ((float4*)(ego + base))[k] = make_float4(f[4 * k], f[4 * k + 1], f[4 * k + 2], f[4 * k + 3]);
        }
        uint4 u0, u1;
        u0.x = (uint_t)f2bf(f[0]) | ((uint_t)f2bf(f[1]) << 16);
        u0.y = (uint_t)f2bf(f[2]) | ((uint_t)f2bf(f[3]) << 16);
        u0.z = (uint_t)f2bf(f[4]) | ((uint_t)f2bf(f[5]) << 16);
        u0.w = (uint_t)f2bf(f[6]) | ((uint_t)f2bf(f[7]) << 16);
        u1.x = (uint_t)f2bf(f[8]) | ((uint_t)f2bf(f[9]) << 16);
        u1.y = (uint_t)f2bf(f[10]) | ((uint_t)f2bf(f[11]) << 16);
        u1.z = (uint_t)f2bf(f[12]) | ((uint_t)f2bf(f[13]) << 16);
        u1.w = (uint_t)f2bf(f[14]) | ((uint_t)f2bf(f[15]) << 16);
        ((uint4*)(egob + base))[0] = u0;
        ((uint4*)(egob + base))[1] = u1;
    }
}

// ===== bucket build: one block per 256-row bin; LDS slot allocation, L2-local writes
__global__ __launch_bounds__(256) void k_bucket(const int2* __restrict__ cellbuf,
                                                const int* __restrict__ cellcnt,
                                                const int* __restrict__ ovcnt,
                                                const int2* __restrict__ ovbuf,
                                                int* __restrict__ cnt,
                                                int2* __restrict__ bkt) {
    __shared__ int lc[RPB];
    int bn = blockIdx.x, tid = threadIdx.x;
    lc[tid] = 0;
    __syncthreads();
    int rbase = bn << 8;
    int f0 = tid, f1 = tid + 256, f2 = tid + 512;
    int c0 = cellcnt[(size_t)f0 * NBIN + bn];
    int c1 = cellcnt[(size_t)f1 * NBIN + bn];
    int c2 = (f2 < FBLK) ? cellcnt[(size_t)f2 * NBIN + bn] : 0;
#pragma unroll
    for (int h = 0; h < 3; h++) {
        int f = (h == 0) ? f0 : ((h == 1) ? f1 : f2);
        int c = (h == 0) ? c0 : ((h == 1) ? c1 : c2);
        const int2* cp = cellbuf + ((size_t)f * NBIN + bn) * CELL_CAP;
        for (int i = 0; i < c; i++) {
            int2 e = cp[i];
            int rl = e.x >> 18;
            int s = atomicAdd(&lc[rl], 1);   // LDS atomic
            if (s < CAP) bkt[(size_t)(rbase + rl) * CAP + s] = make_int2(e.x & 0x3ffff, e.y);
        }
    }
    int oc = min(ovcnt[bn], OV_CAP);
    for (int i = tid; i < oc; i += 256) {
        int2 e = ovbuf[bn * OV_CAP + i];
        int rl = e.x >> 18;
        int s = atomicAdd(&lc[rl], 1);
        if (s < CAP) bkt[(size_t)(rbase + rl) * CAP + s] = make_int2(e.x & 0x3ffff, e.y);
    }
    __syncthreads();
    int r = rbase + tid;
    if (r < N_NUM) cnt[r] = lc[tid];
}

// ===== spmm: 2 rows per 8-lane group, fixed-point int accumulation (order-invariant)
// VS = v * 2^19 (0 for masked slots); A[j] += rn(VS * x[j]); int add is associative.
#define ACC8(A, VS, X) \
    A[0] += __float2int_rn(VS * bfu2f(X.x & 0xffffu)); A[1] += __float2int_rn(VS * bfu2f(X.x >> 16)); \
    A[2] += __float2int_rn(VS * bfu2f(X.y & 0xffffu)); A[3] += __float2int_rn(VS * bfu2f(X.y >> 16)); \
    A[4] += __float2int_rn(VS * bfu2f(X.z & 0xffffu)); A[5] += __float2int_rn(VS * bfu2f(X.z >> 16)); \
    A[6] += __float2int_rn(VS * bfu2f(X.w & 0xffffu)); A[7] += __float2int_rn(VS * bfu2f(X.w >> 16));

__device__ __forceinline__ float row_weight(const float* a, const float* e) {
    float dot = 0.f, nx = 0.f, ne = 0.f;
#pragma unroll
    for (int j = 0; j < 8; j++) {
        dot += a[j] * e[j]; nx += a[j] * a[j]; ne += e[j] * e[j];
    }
#pragma unroll
    for (int m = 1; m < 8; m <<= 1) {
        dot += __shfl_xor(dot, m);
        nx  += __shfl_xor(nx, m);
        ne  += __shfl_xor(ne, m);
    }
    return dot / (fmaxf(sqrtf(nx), EPSV) * fmaxf(sqrtf(ne), EPSV));
}

__global__ __launch_bounds__(256) void k_spmm(const ushort_t* __restrict__ xb,
                                              const ushort_t* __restrict__ egob,
                                              const int* __restrict__ cnt,
                                              const int2* __restrict__ bkt,
                                              ushort_t* __restrict__ xob) {
    int t = blockIdx.x * 256 + threadIdx.x;
    int l = t & 7, g = t >> 3;
    if (g >= N_NUM / 2) return;
    int r0 = g * 2, r1 = r0 + 1;
    int deg0 = min(cnt[r0], CAP), deg1 = min(cnt[r1], CAP);
    const int2* bp0 = bkt + (size_t)r0 * CAP;
    const int2* bp1 = bkt + (size_t)r1 * CAP;
    int dmax = max(deg0, deg1);
    int2 pc0 = bp0[l], pc1 = bp1[l];       // chunk 0 always
    int a0[8], a1[8];
#pragma unroll
    for (int j = 0; j < 8; j++) { a0[j] = 0; a1[j] = 0; }
#pragma unroll
    for (int k = 0; k < 4; k++) {
        if (k * 8 < dmax) {
            bool nn = (k < 3) && ((k + 1) * 8 < dmax);   // group-uniform
            int2 n0 = make_int2(0, 0), n1 = make_int2(0, 0);
            if (nn) { n0 = bp0[l + (k + 1) * 8]; n1 = bp1[l + (k + 1) * 8]; }
            int c0x = pc0.x, c0y = pc0.y, c1x = pc1.x, c1y = pc1.y;
#pragma unroll
            for (int j = 0; j < 8; j++) {
                int cc0 = __shfl(c0x, j, 8);
                float v0 = __int_as_float(__shfl(c0y, j, 8));
                if ((k * 8 + j) >= deg0) { cc0 = 0; v0 = 0.f; }
                uint4 xv = ((const uint4*)xb)[(size_t)cc0 * 8 + l];
                int cc1 = __shfl(c1x, j, 8);
                float v1 = __int_as_float(__shfl(c1y, j, 8));
                if ((k * 8 + j) >= deg1) { cc1 = 0; v1 = 0.f; }
                uint4 yv = ((const uint4*)xb)[(size_t)cc1 * 8 + l];
                float vs0 = v0 * FXS, vs1 = v1 * FXS;
                ACC8(a0, vs0, xv);
                ACC8(a1, vs1, yv);
            }
            if (nn) { pc0 = n0; pc1 = n1; }
        }
    }
#pragma unroll
    for (int rr = 0; rr < 2; rr++) {
        int r = rr ? r1 : r0;
        const int* ai = rr ? a1 : a0;
        float a[8];
#pragma unroll
        for (int j = 0; j < 8; j++) a[j] = (float)ai[j] * FXI;
        float e[8]; dec8(((const uint4*)egob)[(size_t)r * 8 + l], e);
        float wgt = row_weight(a, e);
        uint4 ov;
        ov.x = (uint_t)f2bf(wgt * a[0]) | ((uint_t)f2bf(wgt * a[1]) << 16);
        ov.y = (uint_t)f2bf(wgt * a[2]) | ((uint_t)f2bf(wgt * a[3]) << 16);
        ov.z = (uint_t)f2bf(wgt * a[4]) | ((uint_t)f2bf(wgt * a[5]) << 16);
        ov.w = (uint_t)f2bf(wgt * a[6]) | ((uint_t)f2bf(wgt * a[7]) << 16);
        ((uint4*)xob)[(size_t)r * 8 + l] = ov;
    }
}

// ================= layer 4 + final sum: out = ego + x1 + x2 + x3 + o4 ==============
__global__ __launch_bounds__(256) void k_spmm4(const ushort_t* __restrict__ x3,
                                               const ushort_t* __restrict__ x1,
                                               const ushort_t* __restrict__ x2,
                                               const float* __restrict__ ego,
                                               const int* __restrict__ cnt,
                                               const int2* __restrict__ bkt,
                                               float* __restrict__ out) {
    int t = blockIdx.x * 256 + threadIdx.x;
    int l = t & 7, g = t >> 3;
    if (g >= N_NUM / 2) return;
    int r0 = g * 2, r1 = r0 + 1;
    int deg0 = min(cnt[r0], CAP), deg1 = min(cnt[r1], CAP);
    const int2* bp0 = bkt + (size_t)r0 * CAP;
    const int2* bp1 = bkt + (size_t)r1 * CAP;
    int dmax = max(deg0, deg1);
    int2 pc0 = bp0[l], pc1 = bp1[l];
    int a0[8], a1[8];
#pragma unroll
    for (int j = 0; j < 8; j++) { a0[j] = 0; a1[j] = 0; }
#pragma unroll
    for (int k = 0; k < 4; k++) {
        if (k * 8 < dmax) {
            bool nn = (k < 3) && ((k + 1) * 8 < dmax);
            int2 n0 = make_int2(0, 0), n1 = make_int2(0, 0);
            if (nn) { n0 = bp0[l + (k + 1) * 8]; n1 = bp1[l + (k + 1) * 8]; }
            int c0x = pc0.x, c0y = pc0.y, c1x = pc1.x, c1y = pc1.y;
#pragma unroll
            for (int j = 0; j < 8; j++) {
                int cc0 = __shfl(c0x, j, 8);
                float v0 = __int_as_float(__shfl(c0y, j, 8));
                if ((k * 8 + j) >= deg0) { cc0 = 0; v0 = 0.f; }
                uint4 xv = ((const uint4*)x3)[(size_t)cc0 * 8 + l];
                int cc1 = __shfl(c1x, j, 8);
                float v1 = __int_as_float(__shfl(c1y, j, 8));
                if ((k * 8 + j) >= deg1) { cc1 = 0; v1 = 0.f; }
                uint4 yv = ((const uint4*)x3)[(size_t)cc1 * 8 + l];
                float vs0 = v0 * FXS, vs1 = v1 * FXS;
                ACC8(a0, vs0, xv);
                ACC8(a1, vs1, yv);
            }
            if (nn) { pc0 = n0; pc1 = n1; }
        }
    }
#pragma unroll
    for (int rr = 0; rr < 2; rr++) {
        int r = rr ? r1 : r0;
        const int* ai = rr ? a1 : a0;
        float a[8];
#pragma unroll
        for (int j = 0; j < 8; j++) a[j] = (float)ai[j] * FXI;
        size_t rb = (size_t)r * D + l * 8;
        float e[8];
        float4 e0 = ((const float4*)(ego + rb))[0];
        float4 e1 = ((const float4*)(ego + rb))[1];
        e[0] = e0.x; e[1] = e0.y; e[2] = e0.z; e[3] = e0.w;
        e[4] = e1.x; e[5] = e1.y; e[6] = e1.z; e[7] = e1.w;
        float wgt = row_weight(a, e);
        float s[8];
        float x1d[8], x2d[8], x3d[8];
        dec8(((const uint4*)x1)[(size_t)r * 8 + l], x1d);
        dec8(((const uint4*)x2)[(size_t)r * 8 + l], x2d);
        dec8(((const uint4*)x3)[(size_t)r * 8 + l], x3d);
#pragma unroll
        for (int j = 0; j < 8; j++) s[j] = e[j] + x1d[j] + x2d[j] + x3d[j] + wgt * a[j];
        ((float4*)(out + rb))[0] = make_float4(s[0], s[1], s[2], s[3]);
        ((float4*)(out + rb))[1] = make_float4(s[4], s[5], s[6], s[7]);
    }
}

extern "C" void kernel_launch(void* const* d_in, const int* in_sizes, int n_in,
                              void* d_out, int out_size, void* d_ws, size_t ws_size,
                              hipStream_t stream) {
    const int*   adj_row  = (const int*)d_in[0];
    const int*   adj_col  = (const int*)d_in[1];
    const float* adj_val  = (const float*)d_in[2];
    const float* user_fea = (const float*)d_in[3];
    const float* item_fea = (const float*)d_in[4];
    const float* gu       = (const float*)d_in[5];
    const float* gi       = (const float*)d_in[6];
    const float* mlp_w    = (const float*)d_in[7];
    const float* mlp_b    = (const float*)d_in[8];

    float* out = (float*)d_out;

    char* ws = (char*)d_ws;
    size_t off = 0;
    float*    ego  = (float*)(ws + off);    off += (size_t)N_NUM * D * 4;
    ushort_t* egob = (ushort_t*)(ws + off); off += (size_t)N_NUM * D * 2;
    size_t x1off = off;
    ushort_t* x1   = (ushort_t*)(ws + off); off += (size_t)N_NUM * D * 2;
    ushort_t* x2   = (ushort_t*)(ws + off); off += (size_t)N_NUM * D * 2;
    ushort_t* x3   = (ushort_t*)(ws + off); off += (size_t)N_NUM * D * 2;
    int*      cnt  = (int*)(ws + off);      off += (size_t)N_NUM * 4;
    short*    wbf  = (short*)(ws + off);    off += (size_t)D * F_IT * 2;
    float*    gsu  = (float*)(ws + off);    off += 64 * 4;
    float*    gsi  = (float*)(ws + off);    off += 64 * 4;
    off = (off + 255) & ~(size_t)255;
    int2*     bkt  = (int2*)(ws + off);     off += (size_t)N_NUM * CAP * 8;
    int*      cellcnt = (int*)(ws + off);   off += (size_t)FBLK * NBIN * 4;
    int*      ovcnt   = (int*)(ws + off);   off += (size_t)NBIN * 4;
    int2*     ovbuf   = (int2*)(ws + off);  off += (size_t)NBIN * OV_CAP * 8;
    // cellbuf (44.0 MB) aliases x1..x3 (57.6 MB): dead after k_bucket, before x1 written
    int2*     cellbuf = (int2*)(ws + x1off);

    k_prep<<<97, 256, 0, stream>>>(mlp_w, gu, gi, wbf, gsu, gsi, ovcnt);
    k_mega<<<391 * 9, 256, 0, stream>>>(adj_row, adj_col, adj_val, user_fea, item_fea,
                                        mlp_b, wbf, gsu, gsi,
                                        cellbuf, cellcnt, ovcnt, ovbuf, ego, egob);
    k_bucket<<<NBIN, 256, 0, stream>>>(cellbuf, cellcnt, ovcnt, ovbuf, cnt, bkt);
    int g = (N_NUM / 2 * 8 + 255) / 256;
    k_spmm<<<g, 256, 0, stream>>>(egob, egob, cnt, bkt, x1);
    k_spmm<<<g, 256, 0, stream>>>(x1,   egob, cnt, bkt, x2);
    k_spmm<<<g, 256, 0, stream>>>(x2,   egob, cnt, bkt, x3);
    k_spmm4<<<g, 256, 0, stream>>>(x3, x1, x2, ego, cnt, bkt, out);
}

// Round 3
// 412.124 us; speedup vs baseline: 1.0254x; 1.0254x over previous
//
#include <hip/hip_runtime.h>
#include <hip/hip_bf16.h>

#define U_NUM 100000
#define I_NUM 50000
#define N_NUM 150000
#define E_NUM 1200000
#define D 64
#define F_IT 384
#define CAP 32
#define EPSV 1e-8f
#define FXS 524288.0f          // 2^19 fixed-point scale (deterministic int accumulation)
#define FXI (1.0f / 524288.0f)

// ---- two-level binning geometry ----
#define NBIN 586        // bins of 256 rows: 586*256 = 150016 >= N_NUM
#define RPB 256         // rows per bin (pow2: bin = row >> 8)
#define FBLK 586        // fill blocks, 2048 edges each (8 edges/thread)
#define CELL_CAP 16     // per (fill-block, bin) cell capacity
#define OV_CAP 64       // per-bin overflow side-list capacity

typedef unsigned short ushort_t;
typedef unsigned int uint_t;
typedef short bf16x8 __attribute__((ext_vector_type(8)));
typedef float f32x4 __attribute__((ext_vector_type(4)));

__device__ __forceinline__ ushort_t f2bf(float f) {
    uint_t x = __float_as_uint(f);
    uint_t r = x + 0x7fffu + ((x >> 16) & 1u);   // round-to-nearest-even
    return (ushort_t)(r >> 16);
}
__device__ __forceinline__ float bfu2f(uint_t u_lo16) {
    return __uint_as_float(u_lo16 << 16);
}
__device__ __forceinline__ void dec8(uint4 u, float* f) {
    f[0] = bfu2f(u.x & 0xffffu); f[1] = bfu2f(u.x >> 16);
    f[2] = bfu2f(u.y & 0xffffu); f[3] = bfu2f(u.y >> 16);
    f[4] = bfu2f(u.z & 0xffffu); f[5] = bfu2f(u.z >> 16);
    f[6] = bfu2f(u.w & 0xffffu); f[7] = bfu2f(u.w >> 16);
}

// ================= prep: cast weights + sum global embs + zero ovcnt ===============
__global__ void k_prep(const float* __restrict__ w, const float* __restrict__ gu,
                       const float* __restrict__ gi,
                       short* __restrict__ wbf, float* __restrict__ gsu,
                       float* __restrict__ gsi, int* __restrict__ ovcnt) {
    int b = blockIdx.x, t = threadIdx.x;
    if (b < 96) {
        int i = b * 256 + t;   // exactly 96*256 = 24576 = D*F_IT
        wbf[i] = (short)f2bf(w[i]);
    } else {
        if (t < 64) gsu[t] = gu[t] + gu[64 + t] + gu[128 + t];
        else if (t < 128) { int d = t - 64; gsi[d] = gi[d] + gi[64 + d] + gi[128 + d]; }
        for (int i = t; i < NBIN; i += 256) ovcnt[i] = 0;
    }
}

// ================= mega: edge binning (LDS atomics) + item MLP + user, overlapped ==
#define ITEM_B 782    // ceil(I/64)
#define USER_B 1563   // ceil(U*D/16/256)

__global__ __launch_bounds__(256) void k_mega(
        const int* __restrict__ row, const int* __restrict__ col,
        const float* __restrict__ val,
        const float* __restrict__ ufea, const float* __restrict__ ifea,
        const float* __restrict__ bvec,
        const short* __restrict__ wbf,
        const float* __restrict__ gsu, const float* __restrict__ gsi,
        int2* __restrict__ cellbuf, int* __restrict__ cellcnt,
        int* __restrict__ ovcnt, int2* __restrict__ ovbuf,
        float* __restrict__ ego, ushort_t* __restrict__ egob) {
    __shared__ int bincnt[NBIN];
    int b = blockIdx.x;
    int grp = b / 9, slot = b % 9;
    int tid = threadIdx.x;

    if (slot < 2) {
        // ---------------- fill role: bin 2048 edges via LDS counters ----------------
        int fid = grp * 2 + slot;
        if (fid >= FBLK) return;
        for (int i = tid; i < NBIN; i += 256) bincnt[i] = 0;
        __syncthreads();
        int t = fid * 256 + tid;              // < 150016
        if (t < E_NUM / 8) {                  // E/8 = 150000
#pragma unroll
            for (int k = 0; k < 8; k++) {
                int e = k * (E_NUM / 8) + t;  // strided, coalesced
                int r = row[e], c = col[e];
                float v = val[e];
                int bn = r >> 8;
                int key = c | ((r & 255) << 18);   // col:18b | row_local:8b
                int ls = atomicAdd(&bincnt[bn], 1);      // LDS atomic (fast)
                if (ls < CELL_CAP) {
                    cellbuf[((size_t)fid * NBIN + bn) * CELL_CAP + ls] =
                        make_int2(key, __float_as_int(v));
                } else {
                    int o = atomicAdd(&ovcnt[bn], 1);    // rare global fallback
                    if (o < OV_CAP) ovbuf[bn * OV_CAP + o] = make_int2(key, __float_as_int(v));
                }
            }
        }
        __syncthreads();
        for (int i = tid; i < NBIN; i += 256)
            cellcnt[(size_t)fid * NBIN + i] = min(bincnt[i], CELL_CAP);
    } else if (slot < 4) {
        // ---------------- item MLP role (MFMA, no LDS), 1-deep ifea prefetch -------
        int iid = grp * 2 + (slot - 2);
        if (iid >= ITEM_B) return;
        int wave = tid >> 6, lane = tid & 63;
        int q = lane >> 4, m = lane & 15;
        int ibase = iid * 64 + wave * 16;
        int irow = min(ibase + m, I_NUM - 1);
        const float* arow = ifea + (size_t)irow * F_IT + q * 8;

        f32x4 av[4];
#pragma unroll
        for (int n = 0; n < 4; n++) av[n] = (f32x4){0.f, 0.f, 0.f, 0.f};
        float4 nfa0 = ((const float4*)(arow))[0];
        float4 nfa1 = ((const float4*)(arow))[1];
#pragma unroll
        for (int c = 0; c < 12; c++) {
            float4 fa0 = nfa0, fa1 = nfa1;
            if (c < 11) {
                nfa0 = ((const float4*)(arow + (c + 1) * 32))[0];
                nfa1 = ((const float4*)(arow + (c + 1) * 32))[1];
            }
            bf16x8 af;
            af[0] = (short)f2bf(fa0.x); af[1] = (short)f2bf(fa0.y);
            af[2] = (short)f2bf(fa0.z); af[3] = (short)f2bf(fa0.w);
            af[4] = (short)f2bf(fa1.x); af[5] = (short)f2bf(fa1.y);
            af[6] = (short)f2bf(fa1.z); af[7] = (short)f2bf(fa1.w);
#pragma unroll
            for (int n = 0; n < 4; n++) {
                bf16x8 bf = *(const bf16x8*)(wbf + (size_t)(n * 16 + m) * F_IT + c * 32 + q * 8);
                av[n] = __builtin_amdgcn_mfma_f32_16x16x32_bf16(af, bf, av[n], 0, 0, 0);
            }
        }
        // C/D: col = lane&15 (dim), row = (lane>>4)*4 + reg (item)
#pragma unroll
        for (int n = 0; n < 4; n++) {
            int dim = n * 16 + m;
            float bb = bvec[dim];
            float gg = gsi[dim];
#pragma unroll
            for (int rr = 0; rr < 4; rr++) {
                int item = ibase + q * 4 + rr;
                if (item < I_NUM) {
                    float v = tanhf(av[n][rr] + bb) + gg;
                    size_t o = (size_t)(U_NUM + item) * D + dim;
                    ego[o] = v;
                    egob[o] = f2bf(v);
                }
            }
        }
    } else {
        // ---------------- user role: 16 floats/thread ----------------
        int uid = grp * 5 + (slot - 4);
        if (uid >= USER_B) return;
        int t = uid * 256 + tid;
        size_t base = (size_t)t * 16;
        if (base >= (size_t)U_NUM * D) return;
        int d0 = (int)(base & 63);
        float f[16];
#pragma unroll
        for (int k = 0; k < 4; k++) {
            float4 v = ((const float4*)(ufea + base))[k];
            f[4 * k] = v.x; f[4 * k + 1] = v.y; f[4 * k + 2] = v.z; f[4 * k + 3] = v.w;
        }
#pragma unroll
        for (int j = 0; j < 16; j++) f[j] += gsu[d0 + j];
#pragma unroll
        for (int k = 0; k < 4; k++) {
            ((float4*)(ego + base))[k] = make_float4(f[4 * k], f[4 * k + 1], f[4 * k + 2], f[4 * k + 3]);
        }
        uint4 u0, u1;
        u0.x = (uint_t)f2bf(f[0]) | ((uint_t)f2bf(f[1]) << 16);
        u0.y = (uint_t)f2bf(f[2]) | ((uint_t)f2bf(f[3]) << 16);
        u0.z = (uint_t)f2bf(f[4]) | ((uint_t)f2bf(f[5]) << 16);
        u0.w = (uint_t)f2bf(f[6]) | ((uint_t)f2bf(f[7]) << 16);
        u1.x = (uint_t)f2bf(f[8]) | ((uint_t)f2bf(f[9]) << 16);
        u1.y = (uint_t)f2bf(f[10]) | ((uint_t)f2bf(f[11]) << 16);
        u1.z = (uint_t)f2bf(f[12]) | ((uint_t)f2bf(f[13]) << 16);
        u1.w = (uint_t)f2bf(f[14]) | ((uint_t)f2bf(f[15]) << 16);
        ((uint4*)(egob + base))[0] = u0;
        ((uint4*)(egob + base))[1] = u1;
    }
}

// ===== bucket build: one block per 256-row bin; LDS slot allocation, L2-local writes
__global__ __launch_bounds__(256) void k_bucket(const int2* __restrict__ cellbuf,
                                                const int* __restrict__ cellcnt,
                                                const int* __restrict__ ovcnt,
                                                const int2* __restrict__ ovbuf,
                                                int* __restrict__ cnt,
                                                int2* __restrict__ bkt) {
    __shared__ int lc[RPB];
    int bn = blockIdx.x, tid = threadIdx.x;
    lc[tid] = 0;
    __syncthreads();
    int rbase = bn << 8;
    int f0 = tid, f1 = tid + 256, f2 = tid + 512;
    int c0 = cellcnt[(size_t)f0 * NBIN + bn];
    int c1 = cellcnt[(size_t)f1 * NBIN + bn];
    int c2 = (f2 < FBLK) ? cellcnt[(size_t)f2 * NBIN + bn] : 0;
#pragma unroll
    for (int h = 0; h < 3; h++) {
        int f = (h == 0) ? f0 : ((h == 1) ? f1 : f2);
        int c = (h == 0) ? c0 : ((h == 1) ? c1 : c2);
        const int2* cp = cellbuf + ((size_t)f * NBIN + bn) * CELL_CAP;
        for (int i = 0; i < c; i++) {
            int2 e = cp[i];
            int rl = e.x >> 18;
            int s = atomicAdd(&lc[rl], 1);   // LDS atomic
            if (s < CAP) bkt[(size_t)(rbase + rl) * CAP + s] = make_int2(e.x & 0x3ffff, e.y);
        }
    }
    int oc = min(ovcnt[bn], OV_CAP);
    for (int i = tid; i < oc; i += 256) {
        int2 e = ovbuf[bn * OV_CAP + i];
        int rl = e.x >> 18;
        int s = atomicAdd(&lc[rl], 1);
        if (s < CAP) bkt[(size_t)(rbase + rl) * CAP + s] = make_int2(e.x & 0x3ffff, e.y);
    }
    __syncthreads();
    int r = rbase + tid;
    if (r < N_NUM) cnt[r] = lc[tid];
}

// ===== spmm: ONE row per 8-lane group; per-chunk 8-load register batch (MLP) =======
// VS = v * 2^19 (0 for masked slots); A[j] += rn(VS * x[j]); int add is associative
// -> output bit-stable regardless of bucket slot order.
#define ACC8(A, VS, X) \
    A[0] += __float2int_rn(VS * bfu2f(X.x & 0xffffu)); A[1] += __float2int_rn(VS * bfu2f(X.x >> 16)); \
    A[2] += __float2int_rn(VS * bfu2f(X.y & 0xffffu)); A[3] += __float2int_rn(VS * bfu2f(X.y >> 16)); \
    A[4] += __float2int_rn(VS * bfu2f(X.z & 0xffffu)); A[5] += __float2int_rn(VS * bfu2f(X.z >> 16)); \
    A[6] += __float2int_rn(VS * bfu2f(X.w & 0xffffu)); A[7] += __float2int_rn(VS * bfu2f(X.w >> 16));

__device__ __forceinline__ float row_weight(const float* a, const float* e) {
    float dot = 0.f, nx = 0.f, ne = 0.f;
#pragma unroll
    for (int j = 0; j < 8; j++) {
        dot += a[j] * e[j]; nx += a[j] * a[j]; ne += e[j] * e[j];
    }
#pragma unroll
    for (int m = 1; m < 8; m <<= 1) {
        dot += __shfl_xor(dot, m);
        nx  += __shfl_xor(nx, m);
        ne  += __shfl_xor(ne, m);
    }
    return dot / (fmaxf(sqrtf(nx), EPSV) * fmaxf(sqrtf(ne), EPSV));
}

// gather one row's weighted sum into fixed-point acc a[8] (per lane: dims l*8..l*8+7)
__device__ __forceinline__ void gather_row(const ushort_t* __restrict__ xb,
                                           const int2* __restrict__ bp, int deg, int l,
                                           int* __restrict__ a) {
#pragma unroll
    for (int j = 0; j < 8; j++) a[j] = 0;
#pragma unroll
    for (int k = 0; k < 4; k++) {
        if (k * 8 < deg) {                       // group-uniform
            int2 pc = bp[l + k * 8];
            float vs[8];
            uint4 xu[8];
#pragma unroll
            for (int j = 0; j < 8; j++) {        // batch-issue 8 independent gathers
                int cc = __shfl(pc.x, j, 8);
                float v = __int_as_float(__shfl(pc.y, j, 8));
                if ((k * 8 + j) >= deg) { cc = 0; v = 0.f; }
                vs[j] = v * FXS;
                xu[j] = ((const uint4*)xb)[(size_t)cc * 8 + l];
            }
#pragma unroll
            for (int j = 0; j < 8; j++) { ACC8(a, vs[j], xu[j]); }
        }
    }
}

__global__ __launch_bounds__(256) void k_spmm(const ushort_t* __restrict__ xb,
                                              const ushort_t* __restrict__ egob,
                                              const int* __restrict__ cnt,
                                              const int2* __restrict__ bkt,
                                              ushort_t* __restrict__ xob) {
    int t = blockIdx.x * 256 + threadIdx.x;
    int l = t & 7, r = t >> 3;
    if (r >= N_NUM) return;
    int deg = min(cnt[r], CAP);
    int a[8];
    gather_row(xb, bkt + (size_t)r * CAP, deg, l, a);
    float af[8];
#pragma unroll
    for (int j = 0; j < 8; j++) af[j] = (float)a[j] * FXI;
    float e[8]; dec8(((const uint4*)egob)[(size_t)r * 8 + l], e);
    float wgt = row_weight(af, e);
    uint4 ov;
    ov.x = (uint_t)f2bf(wgt * af[0]) | ((uint_t)f2bf(wgt * af[1]) << 16);
    ov.y = (uint_t)f2bf(wgt * af[2]) | ((uint_t)f2bf(wgt * af[3]) << 16);
    ov.z = (uint_t)f2bf(wgt * af[4]) | ((uint_t)f2bf(wgt * af[5]) << 16);
    ov.w = (uint_t)f2bf(wgt * af[6]) | ((uint_t)f2bf(wgt * af[7]) << 16);
    ((uint4*)xob)[(size_t)r * 8 + l] = ov;
}

// ================= layer 4 + final sum: out = ego + x1 + x2 + x3 + o4 ==============
__global__ __launch_bounds__(256) void k_spmm4(const ushort_t* __restrict__ x3,
                                               const ushort_t* __restrict__ x1,
                                               const ushort_t* __restrict__ x2,
                                               const float* __restrict__ ego,
                                               const int* __restrict__ cnt,
                                               const int2* __restrict__ bkt,
                                               float* __restrict__ out) {
    int t = blockIdx.x * 256 + threadIdx.x;
    int l = t & 7, r = t >> 3;
    if (r >= N_NUM) return;
    int deg = min(cnt[r], CAP);
    int a[8];
    gather_row(x3, bkt + (size_t)r * CAP, deg, l, a);
    float af[8];
#pragma unroll
    for (int j = 0; j < 8; j++) af[j] = (float)a[j] * FXI;
    size_t rb = (size_t)r * D + l * 8;
    float e[8];
    float4 e0 = ((const float4*)(ego + rb))[0];
    float4 e1 = ((const float4*)(ego + rb))[1];
    e[0] = e0.x; e[1] = e0.y; e[2] = e0.z; e[3] = e0.w;
    e[4] = e1.x; e[5] = e1.y; e[6] = e1.z; e[7] = e1.w;
    float wgt = row_weight(af, e);
    float x1d[8], x2d[8], x3d[8];
    dec8(((const uint4*)x1)[(size_t)r * 8 + l], x1d);
    dec8(((const uint4*)x2)[(size_t)r * 8 + l], x2d);
    dec8(((const uint4*)x3)[(size_t)r * 8 + l], x3d);
    float s[8];
#pragma unroll
    for (int j = 0; j < 8; j++) s[j] = e[j] + x1d[j] + x2d[j] + x3d[j] + wgt * af[j];
    ((float4*)(out + rb))[0] = make_float4(s[0], s[1], s[2], s[3]);
    ((float4*)(out + rb))[1] = make_float4(s[4], s[5], s[6], s[7]);
}

extern "C" void kernel_launch(void* const* d_in, const int* in_sizes, int n_in,
                              void* d_out, int out_size, void* d_ws, size_t ws_size,
                              hipStream_t stream) {
    const int*   adj_row  = (const int*)d_in[0];
    const int*   adj_col  = (const int*)d_in[1];
    const float* adj_val  = (const float*)d_in[2];
    const float* user_fea = (const float*)d_in[3];
    const float* item_fea = (const float*)d_in[4];
    const float* gu       = (const float*)d_in[5];
    const float* gi       = (const float*)d_in[6];
    const float* mlp_w    = (const float*)d_in[7];
    const float* mlp_b    = (const float*)d_in[8];

    float* out = (float*)d_out;

    char* ws = (char*)d_ws;
    size_t off = 0;
    float*    ego  = (float*)(ws + off);    off += (size_t)N_NUM * D * 4;
    ushort_t* egob = (ushort_t*)(ws + off); off += (size_t)N_NUM * D * 2;
    size_t x1off = off;
    ushort_t* x1   = (ushort_t*)(ws + off); off += (size_t)N_NUM * D * 2;
    ushort_t* x2   = (ushort_t*)(ws + off); off += (size_t)N_NUM * D * 2;
    ushort_t* x3   = (ushort_t*)(ws + off); off += (size_t)N_NUM * D * 2;
    int*      cnt  = (int*)(ws + off);      off += (size_t)N_NUM * 4;
    short*    wbf  = (short*)(ws + off);    off += (size_t)D * F_IT * 2;
    float*    gsu  = (float*)(ws + off);    off += 64 * 4;
    float*    gsi  = (float*)(ws + off);    off += 64 * 4;
    off = (off + 255) & ~(size_t)255;
    int2*     bkt  = (int2*)(ws + off);     off += (size_t)N_NUM * CAP * 8;
    int*      cellcnt = (int*)(ws + off);   off += (size_t)FBLK * NBIN * 4;
    int*      ovcnt   = (int*)(ws + off);   off += (size_t)NBIN * 4;
    int2*     ovbuf   = (int2*)(ws + off);  off += (size_t)NBIN * OV_CAP * 8;
    // cellbuf (44.0 MB) aliases x1..x3 (57.6 MB): dead after k_bucket, before x1 written
    int2*     cellbuf = (int2*)(ws + x1off);

    k_prep<<<97, 256, 0, stream>>>(mlp_w, gu, gi, wbf, gsu, gsi, ovcnt);
    k_mega<<<391 * 9, 256, 0, stream>>>(adj_row, adj_col, adj_val, user_fea, item_fea,
                                        mlp_b, wbf, gsu, gsi,
                                        cellbuf, cellcnt, ovcnt, ovbuf, ego, egob);
    k_bucket<<<NBIN, 256, 0, stream>>>(cellbuf, cellcnt, ovcnt, ovbuf, cnt, bkt);
    int g = ((size_t)N_NUM * 8 + 255) / 256;   // 4688 blocks: 1 row per 8-lane group
    k_spmm<<<g, 256, 0, stream>>>(egob, egob, cnt, bkt, x1);
    k_spmm<<<g, 256, 0, stream>>>(x1,   egob, cnt, bkt, x2);
    k_spmm<<<g, 256, 0, stream>>>(x2,   egob, cnt, bkt, x3);
    k_spmm4<<<g, 256, 0, stream>>>(x3, x1, x2, ego, cnt, bkt, out);
}

// Round 4
// 410.797 us; speedup vs baseline: 1.0287x; 1.0032x over previous
//
#include <hip/hip_runtime.h>
#include <hip/hip_bf16.h>

#define U_NUM 100000
#define I_NUM 50000
#define N_NUM 150000
#define E_NUM 1200000
#define D 64
#define F_IT 384
#define CAP 32
#define EPSV 1e-8f
#define FXS 524288.0f          // 2^19 fixed-point scale (deterministic int accumulation)
#define FXI (1.0f / 524288.0f)

// ---- two-level binning geometry ----
#define NBIN 586        // bins of 256 rows: 586*256 = 150016 >= N_NUM
#define RPB 256         // rows per bin (pow2: bin = row >> 8)
#define FBLK 586        // fill blocks, 2048 edges each (8 edges/thread)
#define CELL_CAP 16     // per (fill-block, bin) cell capacity
#define OV_CAP 64       // per-bin overflow side-list capacity

typedef unsigned short ushort_t;
typedef unsigned int uint_t;
typedef short bf16x8 __attribute__((ext_vector_type(8)));
typedef float f32x4 __attribute__((ext_vector_type(4)));

__device__ __forceinline__ ushort_t f2bf(float f) {
    uint_t x = __float_as_uint(f);
    uint_t r = x + 0x7fffu + ((x >> 16) & 1u);   // round-to-nearest-even
    return (ushort_t)(r >> 16);
}
__device__ __forceinline__ float bfu2f(uint_t u_lo16) {
    return __uint_as_float(u_lo16 << 16);
}
__device__ __forceinline__ void dec8(uint4 u, float* f) {
    f[0] = bfu2f(u.x & 0xffffu); f[1] = bfu2f(u.x >> 16);
    f[2] = bfu2f(u.y & 0xffffu); f[3] = bfu2f(u.y >> 16);
    f[4] = bfu2f(u.z & 0xffffu); f[5] = bfu2f(u.z >> 16);
    f[6] = bfu2f(u.w & 0xffffu); f[7] = bfu2f(u.w >> 16);
}

// ================= prep: cast weights + sum global embs + zero ovcnt ===============
__global__ void k_prep(const float* __restrict__ w, const float* __restrict__ gu,
                       const float* __restrict__ gi,
                       short* __restrict__ wbf, float* __restrict__ gsu,
                       float* __restrict__ gsi, int* __restrict__ ovcnt) {
    int b = blockIdx.x, t = threadIdx.x;
    if (b < 96) {
        int i = b * 256 + t;   // exactly 96*256 = 24576 = D*F_IT
        wbf[i] = (short)f2bf(w[i]);
    } else {
        if (t < 64) gsu[t] = gu[t] + gu[64 + t] + gu[128 + t];
        else if (t < 128) { int d = t - 64; gsi[d] = gi[d] + gi[64 + d] + gi[128 + d]; }
        for (int i = t; i < NBIN; i += 256) ovcnt[i] = 0;
    }
}

// ================= mega: edge binning (LDS atomics) + item MLP + user, overlapped ==
// launch_bounds(256,4): allow 128 VGPR so the unrolled load batches actually pipeline
#define ITEM_B 782    // ceil(I/64)
#define USER_B 1563   // ceil(U*D/16/256)

__global__ __launch_bounds__(256, 4) void k_mega(
        const int* __restrict__ row, const int* __restrict__ col,
        const float* __restrict__ val,
        const float* __restrict__ ufea, const float* __restrict__ ifea,
        const float* __restrict__ bvec,
        const short* __restrict__ wbf,
        const float* __restrict__ gsu, const float* __restrict__ gsi,
        int2* __restrict__ cellbuf, int* __restrict__ cellcnt,
        int* __restrict__ ovcnt, int2* __restrict__ ovbuf,
        float* __restrict__ ego, ushort_t* __restrict__ egob) {
    __shared__ int bincnt[NBIN];
    int b = blockIdx.x;
    int grp = b / 9, slot = b % 9;
    int tid = threadIdx.x;

    if (slot < 2) {
        // ---------------- fill role: bin 2048 edges via LDS counters ----------------
        int fid = grp * 2 + slot;
        if (fid >= FBLK) return;
        for (int i = tid; i < NBIN; i += 256) bincnt[i] = 0;
        __syncthreads();
        int t = fid * 256 + tid;              // < 150016
        if (t < E_NUM / 8) {                  // E/8 = 150000
            int r[8], c[8];
            float v[8];
#pragma unroll
            for (int k = 0; k < 8; k++) {     // all 24 loads in flight
                int e = k * (E_NUM / 8) + t;  // strided, coalesced
                r[k] = row[e]; c[k] = col[e]; v[k] = val[e];
            }
#pragma unroll
            for (int k = 0; k < 8; k++) {
                int bn = r[k] >> 8;
                int key = c[k] | ((r[k] & 255) << 18);   // col:18b | row_local:8b
                int ls = atomicAdd(&bincnt[bn], 1);      // LDS atomic (fast)
                if (ls < CELL_CAP) {
                    cellbuf[((size_t)fid * NBIN + bn) * CELL_CAP + ls] =
                        make_int2(key, __float_as_int(v[k]));
                } else {
                    int o = atomicAdd(&ovcnt[bn], 1);    // rare global fallback
                    if (o < OV_CAP) ovbuf[bn * OV_CAP + o] = make_int2(key, __float_as_int(v[k]));
                }
            }
        }
        __syncthreads();
        for (int i = tid; i < NBIN; i += 256)
            cellcnt[(size_t)fid * NBIN + i] = min(bincnt[i], CELL_CAP);
    } else if (slot < 4) {
        // ---------------- item MLP role (MFMA, no LDS), 1-deep ifea prefetch -------
        int iid = grp * 2 + (slot - 2);
        if (iid >= ITEM_B) return;
        int wave = tid >> 6, lane = tid & 63;
        int q = lane >> 4, m = lane & 15;
        int ibase = iid * 64 + wave * 16;
        int irow = min(ibase + m, I_NUM - 1);
        const float* arow = ifea + (size_t)irow * F_IT + q * 8;

        f32x4 av[4];
#pragma unroll
        for (int n = 0; n < 4; n++) av[n] = (f32x4){0.f, 0.f, 0.f, 0.f};
        float4 nfa0 = ((const float4*)(arow))[0];
        float4 nfa1 = ((const float4*)(arow))[1];
#pragma unroll
        for (int c = 0; c < 12; c++) {
            float4 fa0 = nfa0, fa1 = nfa1;
            if (c < 11) {
                nfa0 = ((const float4*)(arow + (c + 1) * 32))[0];
                nfa1 = ((const float4*)(arow + (c + 1) * 32))[1];
            }
            bf16x8 af;
            af[0] = (short)f2bf(fa0.x); af[1] = (short)f2bf(fa0.y);
            af[2] = (short)f2bf(fa0.z); af[3] = (short)f2bf(fa0.w);
            af[4] = (short)f2bf(fa1.x); af[5] = (short)f2bf(fa1.y);
            af[6] = (short)f2bf(fa1.z); af[7] = (short)f2bf(fa1.w);
#pragma unroll
            for (int n = 0; n < 4; n++) {
                bf16x8 bf = *(const bf16x8*)(wbf + (size_t)(n * 16 + m) * F_IT + c * 32 + q * 8);
                av[n] = __builtin_amdgcn_mfma_f32_16x16x32_bf16(af, bf, av[n], 0, 0, 0);
            }
        }
        // C/D: col = lane&15 (dim), row = (lane>>4)*4 + reg (item)
#pragma unroll
        for (int n = 0; n < 4; n++) {
            int dim = n * 16 + m;
            float bb = bvec[dim];
            float gg = gsi[dim];
#pragma unroll
            for (int rr = 0; rr < 4; rr++) {
                int item = ibase + q * 4 + rr;
                if (item < I_NUM) {
                    float v = tanhf(av[n][rr] + bb) + gg;
                    size_t o = (size_t)(U_NUM + item) * D + dim;
                    ego[o] = v;
                    egob[o] = f2bf(v);
                }
            }
        }
    } else {
        // ---------------- user role: 16 floats/thread ----------------
        int uid = grp * 5 + (slot - 4);
        if (uid >= USER_B) return;
        int t = uid * 256 + tid;
        size_t base = (size_t)t * 16;
        if (base >= (size_t)U_NUM * D) return;
        int d0 = (int)(base & 63);
        float f[16];
#pragma unroll
        for (int k = 0; k < 4; k++) {
            float4 v = ((const float4*)(ufea + base))[k];
            f[4 * k] = v.x; f[4 * k + 1] = v.y; f[4 * k + 2] = v.z; f[4 * k + 3] = v.w;
        }
#pragma unroll
        for (int j = 0; j < 16; j++) f[j] += gsu[d0 + j];
#pragma unroll
        for (int k = 0; k < 4; k++) {
            ((float4*)(ego + base))[k] = make_float4(f[4 * k], f[4 * k + 1], f[4 * k + 2], f[4 * k + 3]);
        }
        uint4 u0, u1;
        u0.x = (uint_t)f2bf(f[0]) | ((uint_t)f2bf(f[1]) << 16);
        u0.y = (uint_t)f2bf(f[2]) | ((uint_t)f2bf(f[3]) << 16);
        u0.z = (uint_t)f2bf(f[4]) | ((uint_t)f2bf(f[5]) << 16);
        u0.w = (uint_t)f2bf(f[6]) | ((uint_t)f2bf(f[7]) << 16);
        u1.x = (uint_t)f2bf(f[8]) | ((uint_t)f2bf(f[9]) << 16);
        u1.y = (uint_t)f2bf(f[10]) | ((uint_t)f2bf(f[11]) << 16);
        u1.z = (uint_t)f2bf(f[12]) | ((uint_t)f2bf(f[13]) << 16);
        u1.w = (uint_t)f2bf(f[14]) | ((uint_t)f2bf(f[15]) << 16);
        ((uint4*)(egob + base))[0] = u0;
        ((uint4*)(egob + base))[1] = u1;
    }
}

// ===== bucket build: one block per 256-row bin; LDS slot allocation, L2-local writes
__global__ __launch_bounds__(256) void k_bucket(const int2* __restrict__ cellbuf,
                                                const int* __restrict__ cellcnt,
                                                const int* __restrict__ ovcnt,
                                                const int2* __restrict__ ovbuf,
                                                int* __restrict__ cnt,
                                                int2* __restrict__ bkt) {
    __shared__ int lc[RPB];
    int bn = blockIdx.x, tid = threadIdx.x;
    lc[tid] = 0;
    __syncthreads();
    int rbase = bn << 8;
    int f0 = tid, f1 = tid + 256, f2 = tid + 512;
    int c0 = cellcnt[(size_t)f0 * NBIN + bn];
    int c1 = cellcnt[(size_t)f1 * NBIN + bn];
    int c2 = (f2 < FBLK) ? cellcnt[(size_t)f2 * NBIN + bn] : 0;
#pragma unroll
    for (int h = 0; h < 3; h++) {
        int f = (h == 0) ? f0 : ((h == 1) ? f1 : f2);
        int c = (h == 0) ? c0 : ((h == 1) ? c1 : c2);
        const int2* cp = cellbuf + ((size_t)f * NBIN + bn) * CELL_CAP;
        for (int i = 0; i < c; i++) {
            int2 e = cp[i];
            int rl = e.x >> 18;
            int s = atomicAdd(&lc[rl], 1);   // LDS atomic
            if (s < CAP) bkt[(size_t)(rbase + rl) * CAP + s] = make_int2(e.x & 0x3ffff, e.y);
        }
    }
    int oc = min(ovcnt[bn], OV_CAP);
    for (int i = tid; i < oc; i += 256) {
        int2 e = ovbuf[bn * OV_CAP + i];
        int rl = e.x >> 18;
        int s = atomicAdd(&lc[rl], 1);
        if (s < CAP) bkt[(size_t)(rbase + rl) * CAP + s] = make_int2(e.x & 0x3ffff, e.y);
    }
    __syncthreads();
    int r = rbase + tid;
    if (r < N_NUM) cnt[r] = lc[tid];
}

// ===== spmm: ONE row per 8-lane group; chunks 0+1 both issued before any ACC =======
// VS = v * 2^19 (0 for masked slots); A[j] += rn(VS * x[j]); int add is associative
// -> output bit-stable regardless of bucket slot order.
#define ACC8(A, VS, X) \
    A[0] += __float2int_rn(VS * bfu2f(X.x & 0xffffu)); A[1] += __float2int_rn(VS * bfu2f(X.x >> 16)); \
    A[2] += __float2int_rn(VS * bfu2f(X.y & 0xffffu)); A[3] += __float2int_rn(VS * bfu2f(X.y >> 16)); \
    A[4] += __float2int_rn(VS * bfu2f(X.z & 0xffffu)); A[5] += __float2int_rn(VS * bfu2f(X.z >> 16)); \
    A[6] += __float2int_rn(VS * bfu2f(X.w & 0xffffu)); A[7] += __float2int_rn(VS * bfu2f(X.w >> 16));

__device__ __forceinline__ float row_weight(const float* a, const float* e) {
    float dot = 0.f, nx = 0.f, ne = 0.f;
#pragma unroll
    for (int j = 0; j < 8; j++) {
        dot += a[j] * e[j]; nx += a[j] * a[j]; ne += e[j] * e[j];
    }
#pragma unroll
    for (int m = 1; m < 8; m <<= 1) {
        dot += __shfl_xor(dot, m);
        nx  += __shfl_xor(nx, m);
        ne  += __shfl_xor(ne, m);
    }
    return dot / (fmaxf(sqrtf(nx), EPSV) * fmaxf(sqrtf(ne), EPSV));
}

// gather one row's weighted sum into fixed-point acc a[8] (per lane: dims l*8..l*8+7)
// chunks 0 and 1: 16 loads issued back-to-back (64 VGPR in flight), ACC after.
// vs recomputed via shfl at consume time to stay under the 102-VGPR budget.
__device__ __forceinline__ void gather_row(const ushort_t* __restrict__ xb,
                                           const int2* __restrict__ bp, int deg, int l,
                                           int* __restrict__ a) {
#pragma unroll
    for (int j = 0; j < 8; j++) a[j] = 0;
    int2 pc0 = bp[l];
    int2 pc1 = bp[l + 8];          // always in-bounds (CAP=32), same 256B bkt row
    bool has1 = (deg > 8);
    uint4 xu0[8], xu1[8];
#pragma unroll
    for (int j = 0; j < 8; j++) {
        int cc = __shfl(pc0.x, j, 8);
        if (j >= deg) cc = 0;
        xu0[j] = ((const uint4*)xb)[(size_t)cc * 8 + l];
    }
    if (has1) {
#pragma unroll
        for (int j = 0; j < 8; j++) {
            int cc = __shfl(pc1.x, j, 8);
            if (8 + j >= deg) cc = 0;
            xu1[j] = ((const uint4*)xb)[(size_t)cc * 8 + l];
        }
    }
#pragma unroll
    for (int j = 0; j < 8; j++) {
        float v = __int_as_float(__shfl(pc0.y, j, 8));
        if (j >= deg) v = 0.f;
        float vs = v * FXS;
        ACC8(a, vs, xu0[j]);
    }
    if (has1) {
#pragma unroll
        for (int j = 0; j < 8; j++) {
            float v = __int_as_float(__shfl(pc1.y, j, 8));
            if (8 + j >= deg) v = 0.f;
            float vs = v * FXS;
            ACC8(a, vs, xu1[j]);
        }
    }
#pragma unroll
    for (int k = 2; k < 4; k++) {                // rare: P(deg>16) ~ 0.4%
        if (k * 8 < deg) {
            int2 pc = bp[l + k * 8];
            float vs[8];
            uint4 xu[8];
#pragma unroll
            for (int j = 0; j < 8; j++) {
                int cc = __shfl(pc.x, j, 8);
                float v = __int_as_float(__shfl(pc.y, j, 8));
                if ((k * 8 + j) >= deg) { cc = 0; v = 0.f; }
                vs[j] = v * FXS;
                xu[j] = ((const uint4*)xb)[(size_t)cc * 8 + l];
            }
#pragma unroll
            for (int j = 0; j < 8; j++) { ACC8(a, vs[j], xu[j]); }
        }
    }
}

__global__ __launch_bounds__(256, 5) void k_spmm(const ushort_t* __restrict__ xb,
                                                 const ushort_t* __restrict__ egob,
                                                 const int* __restrict__ cnt,
                                                 const int2* __restrict__ bkt,
                                                 ushort_t* __restrict__ xob) {
    int t = blockIdx.x * 256 + threadIdx.x;
    int l = t & 7, r = t >> 3;
    if (r >= N_NUM) return;
    int deg = min(cnt[r], CAP);
    int a[8];
    gather_row(xb, bkt + (size_t)r * CAP, deg, l, a);
    float af[8];
#pragma unroll
    for (int j = 0; j < 8; j++) af[j] = (float)a[j] * FXI;
    float e[8]; dec8(((const uint4*)egob)[(size_t)r * 8 + l], e);
    float wgt = row_weight(af, e);
    uint4 ov;
    ov.x = (uint_t)f2bf(wgt * af[0]) | ((uint_t)f2bf(wgt * af[1]) << 16);
    ov.y = (uint_t)f2bf(wgt * af[2]) | ((uint_t)f2bf(wgt * af[3]) << 16);
    ov.z = (uint_t)f2bf(wgt * af[4]) | ((uint_t)f2bf(wgt * af[5]) << 16);
    ov.w = (uint_t)f2bf(wgt * af[6]) | ((uint_t)f2bf(wgt * af[7]) << 16);
    ((uint4*)xob)[(size_t)r * 8 + l] = ov;
}

// ================= layer 4 + final sum: out = ego + x1 + x2 + x3 + o4 ==============
__global__ __launch_bounds__(256, 5) void k_spmm4(const ushort_t* __restrict__ x3,
                                                  const ushort_t* __restrict__ x1,
                                                  const ushort_t* __restrict__ x2,
                                                  const float* __restrict__ ego,
                                                  const int* __restrict__ cnt,
                                                  const int2* __restrict__ bkt,
                                                  float* __restrict__ out) {
    int t = blockIdx.x * 256 + threadIdx.x;
    int l = t & 7, r = t >> 3;
    if (r >= N_NUM) return;
    int deg = min(cnt[r], CAP);
    int a[8];
    gather_row(x3, bkt + (size_t)r * CAP, deg, l, a);
    float af[8];
#pragma unroll
    for (int j = 0; j < 8; j++) af[j] = (float)a[j] * FXI;
    size_t rb = (size_t)r * D + l * 8;
    float e[8];
    float4 e0 = ((const float4*)(ego + rb))[0];
    float4 e1 = ((const float4*)(ego + rb))[1];
    e[0] = e0.x; e[1] = e0.y; e[2] = e0.z; e[3] = e0.w;
    e[4] = e1.x; e[5] = e1.y; e[6] = e1.z; e[7] = e1.w;
    float wgt = row_weight(af, e);
    float x1d[8], x2d[8], x3d[8];
    dec8(((const uint4*)x1)[(size_t)r * 8 + l], x1d);
    dec8(((const uint4*)x2)[(size_t)r * 8 + l], x2d);
    dec8(((const uint4*)x3)[(size_t)r * 8 + l], x3d);
    float s[8];
#pragma unroll
    for (int j = 0; j < 8; j++) s[j] = e[j] + x1d[j] + x2d[j] + x3d[j] + wgt * af[j];
    ((float4*)(out + rb))[0] = make_float4(s[0], s[1], s[2], s[3]);
    ((float4*)(out + rb))[1] = make_float4(s[4], s[5], s[6], s[7]);
}

extern "C" void kernel_launch(void* const* d_in, const int* in_sizes, int n_in,
                              void* d_out, int out_size, void* d_ws, size_t ws_size,
                              hipStream_t stream) {
    const int*   adj_row  = (const int*)d_in[0];
    const int*   adj_col  = (const int*)d_in[1];
    const float* adj_val  = (const float*)d_in[2];
    const float* user_fea = (const float*)d_in[3];
    const float* item_fea = (const float*)d_in[4];
    const float* gu       = (const float*)d_in[5];
    const float* gi       = (const float*)d_in[6];
    const float* mlp_w    = (const float*)d_in[7];
    const float* mlp_b    = (const float*)d_in[8];

    float* out = (float*)d_out;

    char* ws = (char*)d_ws;
    size_t off = 0;
    float*    ego  = (float*)(ws + off);    off += (size_t)N_NUM * D * 4;
    ushort_t* egob = (ushort_t*)(ws + off); off += (size_t)N_NUM * D * 2;
    size_t x1off = off;
    ushort_t* x1   = (ushort_t*)(ws + off); off += (size_t)N_NUM * D * 2;
    ushort_t* x2   = (ushort_t*)(ws + off); off += (size_t)N_NUM * D * 2;
    ushort_t* x3   = (ushort_t*)(ws + off); off += (size_t)N_NUM * D * 2;
    int*      cnt  = (int*)(ws + off);      off += (size_t)N_NUM * 4;
    short*    wbf  = (short*)(ws + off);    off += (size_t)D * F_IT * 2;
    float*    gsu  = (float*)(ws + off);    off += 64 * 4;
    float*    gsi  = (float*)(ws + off);    off += 64 * 4;
    off = (off + 255) & ~(size_t)255;
    int2*     bkt  = (int2*)(ws + off);     off += (size_t)N_NUM * CAP * 8;
    int*      cellcnt = (int*)(ws + off);   off += (size_t)FBLK * NBIN * 4;
    int*      ovcnt   = (int*)(ws + off);   off += (size_t)NBIN * 4;
    int2*     ovbuf   = (int2*)(ws + off);  off += (size_t)NBIN * OV_CAP * 8;
    // cellbuf (44.0 MB) aliases x1..x3 (57.6 MB): dead after k_bucket, before x1 written
    int2*     cellbuf = (int2*)(ws + x1off);

    k_prep<<<97, 256, 0, stream>>>(mlp_w, gu, gi, wbf, gsu, gsi, ovcnt);
    k_mega<<<391 * 9, 256, 0, stream>>>(adj_row, adj_col, adj_val, user_fea, item_fea,
                                        mlp_b, wbf, gsu, gsi,
                                        cellbuf, cellcnt, ovcnt, ovbuf, ego, egob);
    k_bucket<<<NBIN, 256, 0, stream>>>(cellbuf, cellcnt, ovcnt, ovbuf, cnt, bkt);
    int g = ((size_t)N_NUM * 8 + 255) / 256;   // 4688 blocks: 1 row per 8-lane group
    k_spmm<<<g, 256, 0, stream>>>(egob, egob, cnt, bkt, x1);
    k_spmm<<<g, 256, 0, stream>>>(x1,   egob, cnt, bkt, x2);
    k_spmm<<<g, 256, 0, stream>>>(x2,   egob, cnt, bkt, x3);
    k_spmm4<<<g, 256, 0, stream>>>(x3, x1, x2, ego, cnt, bkt, out);
}